// Round 2
// baseline (584.472 us; speedup 1.0000x reference)
//
#include <hip/hip_runtime.h>
#include <hip/hip_bf16.h>

#define TT 100
#define DD 100
#define PP 10
#define BBATCH 256
#define OC 80

static constexpr float FEPS = 1e-6f;

__device__ __forceinline__ float wsum(float v) {
#pragma unroll
  for (int m = 1; m < 64; m <<= 1) v += __shfl_xor(v, m, 64);
  return v;
}

__device__ __forceinline__ float wmaxr(float v) {
#pragma unroll
  for (int m = 1; m < 64; m <<= 1) v = fmaxf(v, __shfl_xor(v, m, 64));
  return v;
}

__device__ __forceinline__ void wargmax(float& v, int& idx) {
#pragma unroll
  for (int m = 1; m < 64; m <<= 1) {
    float ov = __shfl_xor(v, m, 64);
    int   oi = __shfl_xor(idx, m, 64);
    if (ov > v || (ov == v && oi < idx)) { v = ov; idx = oi; }
  }
}

__global__ __launch_bounds__(256, 2) void match_kernel(
    const float* __restrict__ s1, const float* __restrict__ s2,
    const float* __restrict__ w1, const float* __restrict__ w2,
    const float* __restrict__ w3, const float* __restrict__ w4,
    const float* __restrict__ w5, const float* __restrict__ w6,
    const float* __restrict__ w7, const float* __restrict__ w8,
    float* __restrict__ out)
{
  const int dir  = blockIdx.x & 1;
  const int b    = blockIdx.x >> 1;
  const int doff = dir * DD;
  const int tid  = threadIdx.x;
  const int lane = tid & 63;
  const int wv   = tid >> 6;

  const float* wfull = dir ? w2 : w1;  // full-match weights
  const float* wmax  = dir ? w4 : w3;  // maxpool weights
  const float* wmean = dir ? w6 : w5;  // mean-att weights
  const float* watt2 = dir ? w8 : w7;  // fwd: max-att (w7); bwd: mean-att (w8)

  __shared__ float S2s[TT][DD + 1];   // padded: stride 101 -> conflict-free lanes-over-j
  __shared__ float W2SQ[PP * DD];     // maxpool w^2
  __shared__ float N2PI[TT];          // 1/sqrt(clip(sum s2^2))
  __shared__ float N2WI[TT][PP];      // 1/sqrt(clip(sum s2^2 w^2))
  __shared__ float S1R[16][DD];       // staged s1 rows (16 per block iter)
  __shared__ float CROW[16][DD];      // cos rows, later att rows
  __shared__ int   ARGJ[16];

  // ---- Phase 1: load s2 tile + maxpool w^2 ----
  for (int idx = tid; idx < TT * DD; idx += 256) {
    int j = idx / DD, d = idx - j * DD;
    S2s[j][d] = s2[(j * BBATCH + b) * (2 * DD) + doff + d];
  }
  for (int idx = tid; idx < PP * DD; idx += 256) {
    float v = wmax[idx];
    W2SQ[idx] = v * v;
  }
  __syncthreads();

  // ---- Phase 2: s2 norms (plain + weighted) ----
  for (int task = tid; task < TT + TT * PP; task += 256) {
    if (task < TT) {
      int j = task;
      float a = 0.f;
      for (int d = 0; d < DD; ++d) { float s = S2s[j][d]; a = fmaf(s, s, a); }
      N2PI[j] = 1.0f / sqrtf(fmaxf(a, FEPS));   // exact-ish: feeds argmax-sensitive cos
    } else {
      int q = task - TT; int j = q / PP, p = q - j * PP;
      float a = 0.f;
      for (int d = 0; d < DD; ++d) { float s = S2s[j][d]; a = fmaf(s * s, W2SQ[p * DD + d], a); }
      N2WI[j][p] = rsqrtf(fmaxf(a, FEPS));      // continuous use: rsqrt fine
    }
  }
  __syncthreads();

  const int  j0   = lane;
  const int  j1   = 64 + lane;
  const bool act1 = (j1 < TT);          // lanes 0..35 own second j
  const int  j1c  = act1 ? j1 : (TT - 1);
  const int  d0   = lane;
  const bool actd = (64 + lane) < DD;   // lanes 0..35 own second d
  const int  d1   = actd ? (64 + lane) : (DD - 1);

  // ---- Phase 3: 7 block-iters x (4 waves x 4 rows) ----
  for (int t = 0; t < 7; ++t) {
    const int rbase = t * 16;
    for (int idx = tid; idx < 16 * DD; idx += 256) {
      int r = idx / DD, d = idx - r * DD;
      int row = rbase + r;
      S1R[r][d] = (row < TT) ? s1[(row * BBATCH + b) * (2 * DD) + doff + d] : 0.f;
    }
    __syncthreads();

    const int g = t * 4 + wv;
    const int i0 = g * 4;
    const int sl = wv * 4;
    const bool active = (g < 25);

    float rs[4] = {0, 0, 0, 0};
    float att0[4] = {0, 0, 0, 0}, att1[4] = {0, 0, 0, 0};

    // ---- Sub-phase A+B+C: norms, main dot pass, cos rows + argmax + maxpool ----
    if (active) {
      // A. s1 norms for 4 rows (plain exact-ish, weighted rsqrt) via butterflies
      float n1pi[4], n1wi[4][PP];
#pragma unroll
      for (int r = 0; r < 4; ++r) {
        float a0 = S1R[sl + r][d0];
        float a1 = S1R[sl + r][actd ? (64 + lane) : 0];
        a1 = actd ? a1 : 0.f;
        float sq0 = a0 * a0, sq1 = a1 * a1;
        float tot = wsum(sq0 + sq1);
        n1pi[r] = 1.0f / sqrtf(fmaxf(tot, FEPS));
#pragma unroll
        for (int p = 0; p < PP; ++p) {
          float wq0 = W2SQ[p * DD + d0];
          float wq1 = W2SQ[p * DD + (actd ? (64 + lane) : 0)];
          float s = sq0 * wq0 + (actd ? sq1 * wq1 : 0.f);
          n1wi[r][p] = rsqrtf(fmaxf(wsum(s), FEPS));
        }
      }

      // B. main dot pass: per lane two j's, per wave 4 rows, plain + 10 weighted accs
      float dot0[4] = {0, 0, 0, 0}, dot1[4] = {0, 0, 0, 0};
      float wa0[4][PP] = {{0}}, wa1[4][PP] = {{0}};
#pragma unroll 2
      for (int d = 0; d < DD; ++d) {
        float s2a = S2s[j0][d];
        float s2b = S2s[j1c][d];
        float wvp[PP];
#pragma unroll
        for (int p = 0; p < PP; ++p) wvp[p] = W2SQ[p * DD + d];
#pragma unroll
        for (int r = 0; r < 4; ++r) {
          float s1v = S1R[sl + r][d];
          float ta = s1v * s2a, tb = s1v * s2b;
          dot0[r] += ta; dot1[r] += tb;
#pragma unroll
          for (int p = 0; p < PP; ++p) {
            wa0[r][p] = fmaf(ta, wvp[p], wa0[r][p]);
            wa1[r][p] = fmaf(tb, wvp[p], wa1[r][p]);
          }
        }
      }

      // C. finalize rows: cos rows, rowsum, argmax, maxpool outputs
#pragma unroll
      for (int r = 0; r < 4; ++r) {
        float c0 = dot0[r] * (n1pi[r] * N2PI[j0]);
        float c1 = dot1[r] * (n1pi[r] * N2PI[j1c]);
        CROW[sl + r][j0] = c0;
        if (act1) CROW[sl + r][j1] = c1;
        rs[r] = wsum(c0 + (act1 ? c1 : 0.f));

        float mv = c0; int mi = j0;
        if (act1 && (c1 > mv)) { mv = c1; mi = j1; }
        wargmax(mv, mi);
        if (lane == 0) ARGJ[sl + r] = mi;

#pragma unroll
        for (int p = 0; p < PP; ++p) {
          float v0 = wa0[r][p] * N2WI[j0][p];
          float v1 = act1 ? wa1[r][p] * N2WI[j1c][p] : -3.4e38f;
          float m = wmaxr(fmaxf(v0, v1));
          if (lane == 0) {
            out[((i0 + r) * BBATCH + b) * OC + 20 + dir * PP + p] = m * n1wi[r][p];
          }
        }
      }
    }
    __syncthreads();  // cos rows + ARGJ visible block-wide

    // ---- Sub-phase D: mean-att accumulation (lanes over d) ----
    if (active) {
      for (int j = 0; j < TT; ++j) {
        float s2a = S2s[j][d0];
        float s2b = S2s[j][d1];
#pragma unroll
        for (int r = 0; r < 4; ++r) {
          float c = CROW[sl + r][j];
          att0[r] = fmaf(c, s2a, att0[r]);
          att1[r] = fmaf(c, s2b, att1[r]);
        }
      }
    }
    __syncthreads();  // all cos reads done before overwrite

    if (active) {
#pragma unroll
      for (int r = 0; r < 4; ++r) {
        float inv = 1.0f / (rs[r] + FEPS);
        CROW[sl + r][d0] = att0[r] * inv;
        if (actd) CROW[sl + r][64 + lane] = att1[r] * inv;
      }
    }
    __syncthreads();  // att rows visible

    // ---- Sub-phase E: epilogue: 120 tasks = 4 rows x {full, mean-att, att2} x 10 p
    if (active) {
      for (int tk = lane; tk < 120; tk += 64) {
        int r = tk / 30;
        int q = tk - r * 30;
        int set = q / PP;
        int p = q - set * PP;
        const float* wrow = (set == 0 ? wfull : (set == 1 ? wmean : watt2)) + p * DD;
        // reference quirk: s2.reshape(-1,D)[argmax] == s2f[0, argmax, :] (fwd only)
        const float* gat = s2 + ARGJ[sl + r] * (2 * DD);
        float num = 0.f, nx = 0.f, ny = 0.f;
        for (int d = 0; d < DD; ++d) {
          float x = S1R[sl + r][d];
          float y;
          if (set == 0)      y = S2s[TT - 1][d];
          else if (set == 1) y = CROW[sl + r][d];
          else               y = (dir == 0) ? gat[d] : CROW[sl + r][d];
          float w = wrow[d];
          float w2v = w * w;
          num = fmaf(x * y, w2v, num);
          nx  = fmaf(x * x, w2v, nx);
          ny  = fmaf(y * y, w2v, ny);
        }
        float c = num * rsqrtf(fmaxf(nx, FEPS)) * rsqrtf(fmaxf(ny, FEPS));
        int ch = (set == 0 ? 0 : (set == 1 ? 40 : 60)) + dir * PP + p;
        out[((i0 + r) * BBATCH + b) * OC + ch] = c;
      }
    }
    __syncthreads();  // before next-t staging overwrites S1R
  }
}

extern "C" void kernel_launch(void* const* d_in, const int* in_sizes, int n_in,
                              void* d_out, int out_size, void* d_ws, size_t ws_size,
                              hipStream_t stream) {
  const float* s1 = (const float*)d_in[0];
  const float* s2 = (const float*)d_in[1];
  match_kernel<<<dim3(512), dim3(256), 0, stream>>>(
      s1, s2,
      (const float*)d_in[2], (const float*)d_in[3],
      (const float*)d_in[4], (const float*)d_in[5],
      (const float*)d_in[6], (const float*)d_in[7],
      (const float*)d_in[8], (const float*)d_in[9],
      (float*)d_out);
}

// Round 3
// 473.386 us; speedup vs baseline: 1.2347x; 1.2347x over previous
//
#include <hip/hip_runtime.h>

#define TT 100
#define DD 100
#define DC 25      // DD/4
#define PP 10
#define BBATCH 256
#define OC 80

typedef float v2f __attribute__((ext_vector_type(2)));
typedef float v4f __attribute__((ext_vector_type(4)));

static constexpr float FEPS = 1e-6f;

__device__ __forceinline__ float wsum(float v) {
#pragma unroll
  for (int m = 1; m < 64; m <<= 1) v += __shfl_xor(v, m, 64);
  return v;
}

__device__ __forceinline__ float wmaxr(float v) {
#pragma unroll
  for (int m = 1; m < 64; m <<= 1) v = fmaxf(v, __shfl_xor(v, m, 64));
  return v;
}

__device__ __forceinline__ void wargmax(float& v, int& idx) {
#pragma unroll
  for (int m = 1; m < 64; m <<= 1) {
    float ov = __shfl_xor(v, m, 64);
    int   oi = __shfl_xor(idx, m, 64);
    if (ov > v || (ov == v && oi < idx)) { v = ov; idx = oi; }
  }
}

__global__ __launch_bounds__(256, 2) void match_kernel(
    const float* __restrict__ s1, const float* __restrict__ s2,
    const float* __restrict__ w1, const float* __restrict__ w2,
    const float* __restrict__ w3, const float* __restrict__ w4,
    const float* __restrict__ w5, const float* __restrict__ w6,
    const float* __restrict__ w7, const float* __restrict__ w8,
    float* __restrict__ out)
{
  const int dir  = blockIdx.x & 1;
  const int b    = blockIdx.x >> 1;
  const int doff = dir * DD;
  const int tid  = threadIdx.x;
  const int lane = tid & 63;
  const int wv   = tid >> 6;

  const float* wfull = dir ? w2 : w1;
  const float* wmax  = dir ? w4 : w3;
  const float* wmean = dir ? w6 : w5;
  const float* watt2 = dir ? w8 : w7;   // fwd: max-att (w7); bwd: mean-att (w8)

  // s2 in d-chunked layout: d = 4c+k. j-stride = 16B (b128-able, conflict-free
  // lane-over-j); chunk stride = 101*4 = 404 dwords == 20 mod 32 (2-way free
  // for lane-over-d b32 reads in phase D).
  __shared__ __align__(16) float S2V[DC][TT + 1][4];
  __shared__ __align__(16) float W2SQ[PP][DD];
  __shared__ float N2PI[TT];
  __shared__ float N2WI[TT][11];        // padded: (11j+p)%32 -> 2-way free
  __shared__ __align__(16) float S1R[16][DD];
  __shared__ __align__(16) float CROW[16][DD];
  __shared__ float N1PI[16];
  __shared__ float N1WI[16][PP];
  __shared__ int   ARGJ[16];

  // ---- Phase 1: load s2 tile (d-chunked) + maxpool w^2 ----
  for (int idx = tid; idx < TT * DD; idx += 256) {
    int j = idx / DD, d = idx - j * DD;
    S2V[d >> 2][j][d & 3] = s2[(j * BBATCH + b) * (2 * DD) + doff + d];
  }
  for (int idx = tid; idx < PP * DD; idx += 256) {
    int p = idx / DD, d = idx - p * DD;
    float v = wmax[idx];
    W2SQ[p][d] = v * v;
  }
  __syncthreads();

  // ---- Phase 2: s2 norms (plain exact-ish + weighted rsqrt), float4 reads ----
  for (int task = tid; task < TT + TT * PP; task += 256) {
    if (task < TT) {
      int j = task;
      float a = 0.f;
      for (int c = 0; c < DC; ++c) {
        v4f f = *(const v4f*)&S2V[c][j][0];
#pragma unroll
        for (int k = 0; k < 4; ++k) a = fmaf(f[k], f[k], a);
      }
      N2PI[j] = 1.0f / sqrtf(fmaxf(a, FEPS));   // feeds argmax-sensitive cos
    } else {
      int q = task - TT; int j = q / PP, p = q - j * PP;
      float a = 0.f;
      for (int c = 0; c < DC; ++c) {
        v4f f = *(const v4f*)&S2V[c][j][0];
        v4f w = *(const v4f*)&W2SQ[p][4 * c];
#pragma unroll
        for (int k = 0; k < 4; ++k) a = fmaf(f[k] * f[k], w[k], a);
      }
      N2WI[j][p] = rsqrtf(fmaxf(a, FEPS));
    }
  }
  __syncthreads();

  const int  j0   = lane;
  const int  j1   = 64 + lane;
  const bool act1 = (j1 < TT);
  const int  j1c  = act1 ? j1 : (TT - 1);
  const bool actd = (64 + lane) < DD;
  const int  d1   = actd ? (64 + lane) : (DD - 1);
  const int  c0i  = lane >> 2, k0 = lane & 3;      // phase-D d0 = lane
  const int  c1i  = d1 >> 2,   k1 = d1 & 3;        // phase-D d1

  // ---- Phase 3: 7 block-iters x (4 waves x 4 rows) ----
  for (int t = 0; t < 7; ++t) {
    const int rbase = t * 16;
    for (int idx = tid; idx < 16 * DD; idx += 256) {
      int r = idx / DD, d = idx - r * DD;
      int row = rbase + r;
      S1R[r][d] = (row < TT) ? s1[(row * BBATCH + b) * (2 * DD) + doff + d] : 0.f;
    }
    __syncthreads();

    // cooperative s1 norms -> LDS (replaces 44 butterfly chains per wave)
    for (int task = tid; task < 16 * 11; task += 256) {
      int rr = task / 11, q = task - rr * 11;
      if (q == 0) {
        float a = 0.f;
        for (int c = 0; c < DC; ++c) {
          v4f f = *(const v4f*)&S1R[rr][4 * c];
#pragma unroll
          for (int k = 0; k < 4; ++k) a = fmaf(f[k], f[k], a);
        }
        N1PI[rr] = 1.0f / sqrtf(fmaxf(a, FEPS));
      } else {
        int p = q - 1;
        float a = 0.f;
        for (int c = 0; c < DC; ++c) {
          v4f f = *(const v4f*)&S1R[rr][4 * c];
          v4f w = *(const v4f*)&W2SQ[p][4 * c];
#pragma unroll
          for (int k = 0; k < 4; ++k) a = fmaf(f[k] * f[k], w[k], a);
        }
        N1WI[rr][p] = rsqrtf(fmaxf(a, FEPS));
      }
    }
    __syncthreads();

    const int g = t * 4 + wv;
    const int i0 = g * 4;
    const int sl = wv * 4;
    const bool active = (g < 25);

    float rs[4] = {0, 0, 0, 0};
    v2f attp[4] = {{0, 0}, {0, 0}, {0, 0}, {0, 0}};

    // ---- Phase B: packed (j0,j1) main dot pass, b128 LDS reads ----
    if (active) {
      v2f dotp[4] = {{0, 0}, {0, 0}, {0, 0}, {0, 0}};
      v2f wap[4][PP];
#pragma unroll
      for (int r = 0; r < 4; ++r)
#pragma unroll
        for (int p = 0; p < PP; ++p) wap[r][p] = (v2f){0.f, 0.f};

      for (int c = 0; c < DC; ++c) {
        v4f s2a4 = *(const v4f*)&S2V[c][j0][0];
        v4f s2b4 = *(const v4f*)&S2V[c][j1c][0];
        v4f wq[PP];
#pragma unroll
        for (int p = 0; p < PP; ++p) wq[p] = *(const v4f*)&W2SQ[p][4 * c];
        v4f s1v[4];
#pragma unroll
        for (int r = 0; r < 4; ++r) s1v[r] = *(const v4f*)&S1R[sl + r][4 * c];
#pragma unroll
        for (int k = 0; k < 4; ++k) {
          v2f s2ab; s2ab.x = s2a4[k]; s2ab.y = s2b4[k];
#pragma unroll
          for (int r = 0; r < 4; ++r) {
            v2f s1xx; s1xx.x = s1v[r][k]; s1xx.y = s1v[r][k];
            v2f ta = s1xx * s2ab;     // v_pk_mul_f32
            dotp[r] += ta;            // v_pk_add_f32 (same rounding as scalar path)
#pragma unroll
            for (int p = 0; p < PP; ++p) {
              v2f wk; wk.x = wq[p][k]; wk.y = wq[p][k];
              wap[r][p] = __builtin_elementwise_fma(ta, wk, wap[r][p]);  // v_pk_fma_f32
            }
          }
        }
      }

      // ---- Phase C: cos rows, rowsum, argmax, maxpool outputs ----
#pragma unroll
      for (int r = 0; r < 4; ++r) {
        float n1pi_r = N1PI[sl + r];
        float c0 = dotp[r].x * (n1pi_r * N2PI[j0]);
        float c1 = dotp[r].y * (n1pi_r * N2PI[j1c]);
        CROW[sl + r][j0] = c0;
        if (act1) CROW[sl + r][j1] = c1;
        rs[r] = wsum(c0 + (act1 ? c1 : 0.f));

        float mv = c0; int mi = j0;
        if (act1 && (c1 > mv)) { mv = c1; mi = j1; }
        wargmax(mv, mi);
        if (lane == 0) ARGJ[sl + r] = mi;

#pragma unroll
        for (int p = 0; p < PP; ++p) {
          float v0 = wap[r][p].x * N2WI[j0][p];
          float v1 = act1 ? wap[r][p].y * N2WI[j1c][p] : -3.4e38f;
          float m = wmaxr(fmaxf(v0, v1));
          if (lane == 0) {
            out[((i0 + r) * BBATCH + b) * OC + 20 + dir * PP + p] = m * N1WI[sl + r][p];
          }
        }
      }
    }
    __syncthreads();  // cos rows + ARGJ visible block-wide

    // ---- Phase D: mean-att accumulation, packed (d0,d1) ----
    if (active) {
      for (int j = 0; j < TT; ++j) {
        v2f s2ab; s2ab.x = S2V[c0i][j][k0]; s2ab.y = S2V[c1i][j][k1];
#pragma unroll
        for (int r = 0; r < 4; ++r) {
          float cv = CROW[sl + r][j];
          v2f cc; cc.x = cv; cc.y = cv;
          attp[r] = __builtin_elementwise_fma(cc, s2ab, attp[r]);
        }
      }
    }
    __syncthreads();  // all cos reads done before overwrite

    if (active) {
#pragma unroll
      for (int r = 0; r < 4; ++r) {
        float inv = 1.0f / (rs[r] + FEPS);
        CROW[sl + r][lane] = attp[r].x * inv;
        if (actd) CROW[sl + r][64 + lane] = attp[r].y * inv;
      }
    }
    __syncthreads();  // att rows visible

    // ---- Phase E: epilogue: 120 tasks = 4 rows x {full, mean-att, att2} x 10 p
    if (active) {
      for (int tk = lane; tk < 120; tk += 64) {
        int r = tk / 30;
        int q = tk - r * 30;
        int set = q / PP;
        int p = q - set * PP;
        const float* wrow = (set == 0 ? wfull : (set == 1 ? wmean : watt2)) + p * DD;
        // reference quirk: s2.reshape(-1,D)[argmax] == s2f[0, argmax, :] (fwd only)
        const float* gat = s2 + ARGJ[sl + r] * (2 * DD);
        float num = 0.f, nx = 0.f, ny = 0.f;
        for (int c = 0; c < DC; ++c) {
          v4f x4 = *(const v4f*)&S1R[sl + r][4 * c];
          v4f y4;
          if (set == 0)                     y4 = *(const v4f*)&S2V[c][TT - 1][0];
          else if (set == 1 || dir == 1)    y4 = *(const v4f*)&CROW[sl + r][4 * c];
          else                              y4 = *(const v4f*)&gat[4 * c];
          v4f w4 = *(const v4f*)&wrow[4 * c];
#pragma unroll
          for (int k = 0; k < 4; ++k) {
            float w2v = w4[k] * w4[k];
            num = fmaf(x4[k] * y4[k], w2v, num);
            nx  = fmaf(x4[k] * x4[k], w2v, nx);
            ny  = fmaf(y4[k] * y4[k], w2v, ny);
          }
        }
        float cres = num * rsqrtf(fmaxf(nx, FEPS)) * rsqrtf(fmaxf(ny, FEPS));
        int ch = (set == 0 ? 0 : (set == 1 ? 40 : 60)) + dir * PP + p;
        out[((i0 + r) * BBATCH + b) * OC + ch] = cres;
      }
    }
    __syncthreads();  // before next-t staging overwrites S1R
  }
}

extern "C" void kernel_launch(void* const* d_in, const int* in_sizes, int n_in,
                              void* d_out, int out_size, void* d_ws, size_t ws_size,
                              hipStream_t stream) {
  const float* s1 = (const float*)d_in[0];
  const float* s2 = (const float*)d_in[1];
  match_kernel<<<dim3(512), dim3(256), 0, stream>>>(
      s1, s2,
      (const float*)d_in[2], (const float*)d_in[3],
      (const float*)d_in[4], (const float*)d_in[5],
      (const float*)d_in[6], (const float*)d_in[7],
      (const float*)d_in[8], (const float*)d_in[9],
      (float*)d_out);
}